// Round 2
// baseline (550.430 us; speedup 1.0000x reference)
//
#include <hip/hip_runtime.h>
#include <hip/hip_bf16.h>
#include <cstdint>
#include <cstddef>

#define NEG_INF (-1.0e9f)

typedef __attribute__((ext_vector_type(8))) short bf16x8;
typedef __attribute__((ext_vector_type(4))) float f32x4;

constexpr int BB = 64;     // batch
constexpr int NN = 2048;   // seq len
constexpr int HH = 512;    // h dim
constexpr int DD = 512;    // enc dim (GEMM K)
constexpr int AA = 512;    // attention dim (GEMM N)

__device__ __forceinline__ float fast_rcp(float x) {
#if __has_builtin(__builtin_amdgcn_rcpf)
  return __builtin_amdgcn_rcpf(x);
#else
  return 1.f / x;
#endif
}

__device__ __forceinline__ float fast_tanh(float x) {
  float e = __expf(2.f * fabsf(x));
  float t = 1.f - 2.f * fast_rcp(e + 1.f);
  return copysignf(t, x);
}

// 8 fp32 -> bf16x8 via packed HW cvt
__device__ __forceinline__ bf16x8 pack8(const float4& lo, const float4& hi) {
  __hip_bfloat162 a = __float22bfloat162_rn(float2{lo.x, lo.y});
  __hip_bfloat162 b = __float22bfloat162_rn(float2{lo.z, lo.w});
  __hip_bfloat162 c = __float22bfloat162_rn(float2{hi.x, hi.y});
  __hip_bfloat162 d = __float22bfloat162_rn(float2{hi.z, hi.w});
  union { unsigned int w[4]; bf16x8 v; } u;
  __builtin_memcpy(&u.w[0], &a, 4);
  __builtin_memcpy(&u.w[1], &b, 4);
  __builtin_memcpy(&u.w[2], &c, 4);
  __builtin_memcpy(&u.w[3], &d, 4);
  return u.v;
}

// -------- We -> bf16 (512 KB ws) --------
__global__ __launch_bounds__(256)
void we_cast_kernel(const float* __restrict__ We, unsigned short* __restrict__ web) {
  int i = (blockIdx.x * 256 + threadIdx.x) * 8;
  if (i >= AA * DD) return;
  float4 s0 = *(const float4*)(We + i);
  float4 s1 = *(const float4*)(We + i + 4);
  *(bf16x8*)(web + i) = pack8(s0, s1);
}

// -------- proj_h --------
__global__ __launch_bounds__(256)
void proj_h_kernel(const float* __restrict__ h, const float* __restrict__ Wh,
                   float* __restrict__ ph) {
  __shared__ float hL[HH];
  const int b = blockIdx.x;
  hL[threadIdx.x]       = h[b * HH + threadIdx.x];
  hL[threadIdx.x + 256] = h[b * HH + threadIdx.x + 256];
  __syncthreads();
  const int a = blockIdx.y * 256 + threadIdx.x;
  const float4* wr = (const float4*)(Wh + (size_t)a * HH);
  float acc = 0.f;
  #pragma unroll 4
  for (int j = 0; j < HH / 4; ++j) {
    float4 w = wr[j];
    acc += w.x * hL[4*j] + w.y * hL[4*j+1] + w.z * hL[4*j+2] + w.w * hL[4*j+3];
  }
  ph[b * AA + a] = acc;
}

// -------- fused scores v2: 128-row blocks, 8 waves, K-chunked double-buffered --------
// Wave (wr,wc): rows [wr*64,+64) x cols [wc*128,+128). Inner loop identical to the
// verified 64-row kernel (af[4] x bfr[8] x acc[4][8]). B L2 traffic halves vs R=64;
// staging overlaps compute (T14: issue loads -> MFMA -> pack/ds_write -> barrier).
__global__ __launch_bounds__(512, 2)
void scores_fullk(const float* __restrict__ enc, const unsigned short* __restrict__ web,
                  const float* __restrict__ ph, const float* __restrict__ vvec,
                  float* __restrict__ scores) {
  constexpr int RR  = 128;   // rows per block
  constexpr int CK  = 128;   // k-chunk (ushorts)
  constexpr int LDK = 136;   // padded chunk row stride (ushorts) -> 272 B, bank step 4

  __shared__ unsigned short As[2][RR * LDK];  // 69,632 B
  __shared__ float sred[4][RR];               // 2 KB

  const int tid  = threadIdx.x;
  const int lane = tid & 63;
  const int wid  = tid >> 6;      // 0..7
  const int wr   = wid >> 2;      // 0..1  row-group
  const int wc   = wid & 3;       // 0..3  col-group
  const int c    = lane & 15;
  const int quad = lane >> 4;

  const int r0 = blockIdx.x * RR;
  const int b  = r0 >> 11;        // 128 | 2048, tiles never cross batch

  // staging: thread covers rows {srow, srow+32, srow+64, srow+96}, 8 floats each
  const int srow = (tid * 8) >> 7;
  const int scol = (tid * 8) & 127;
  const float* encBase = enc + (size_t)r0 * DD;

  float4 lo[4], hi[4];

  auto LOADREGS = [&](int kc) {
    #pragma unroll
    for (int s = 0; s < 4; ++s) {
      const float* p = encBase + (size_t)(srow + s * 32) * DD + kc * CK + scol;
      lo[s] = *(const float4*)p;
      hi[s] = *(const float4*)(p + 4);
    }
  };
  auto WRITE = [&](int buf) {
    #pragma unroll
    for (int s = 0; s < 4; ++s)
      *(bf16x8*)&As[buf][(srow + s * 32) * LDK + scol] = pack8(lo[s], hi[s]);
  };

  // per-lane fragment bases
  const unsigned short* bBase = web + ((size_t)(wc * 128 + c)) * DD + quad * 8;

  float pp[8], vv[8];
  #pragma unroll
  for (int j = 0; j < 8; ++j) {
    const int col = wc * 128 + j * 16 + c;
    pp[j] = ph[b * AA + col];
    vv[j] = vvec[col];
  }

  f32x4 acc[4][8];
  #pragma unroll
  for (int i = 0; i < 4; ++i)
    #pragma unroll
    for (int j = 0; j < 8; ++j)
      acc[i][j] = (f32x4){0.f, 0.f, 0.f, 0.f};

  // prologue: stage chunk 0
  LOADREGS(0);
  WRITE(0);
  __syncthreads();

  #pragma unroll
  for (int kc = 0; kc < 4; ++kc) {
    const int cur = kc & 1;
    if (kc < 3) LOADREGS(kc + 1);              // issue next chunk's loads early

    const unsigned short* aB = &As[cur][(wr * 64 + c) * LDK + quad * 8];
    const int kglob = kc * CK;
    #pragma unroll
    for (int k0 = 0; k0 < CK; k0 += 32) {
      bf16x8 bfr[8];
      #pragma unroll
      for (int j = 0; j < 8; ++j)
        bfr[j] = *(const bf16x8*)(bBase + (size_t)(j * 16) * DD + kglob + k0);
      bf16x8 af[4];
      #pragma unroll
      for (int i = 0; i < 4; ++i)
        af[i] = *(const bf16x8*)(aB + i * 16 * LDK + k0);
      #pragma unroll
      for (int i = 0; i < 4; ++i)
        #pragma unroll
        for (int j = 0; j < 8; ++j)
          acc[i][j] = __builtin_amdgcn_mfma_f32_16x16x32_bf16(af[i], bfr[j], acc[i][j], 0, 0, 0);
    }

    if (kc < 3) WRITE(cur ^ 1);                // pack + ds_write after compute
    __syncthreads();
  }

  // epilogue: per-row partial = sum_cols v*tanh(acc+ph); C/D: row=quad*4+r, col=c
  #pragma unroll
  for (int i = 0; i < 4; ++i) {
    #pragma unroll
    for (int r = 0; r < 4; ++r) {
      float p = 0.f;
      #pragma unroll
      for (int j = 0; j < 8; ++j)
        p += vv[j] * fast_tanh(acc[i][j][r] + pp[j]);
      p += __shfl_xor(p, 1, 64);
      p += __shfl_xor(p, 2, 64);
      p += __shfl_xor(p, 4, 64);
      p += __shfl_xor(p, 8, 64);
      if (c == 0) sred[wc][wr * 64 + i * 16 + quad * 4 + r] = p;
    }
  }
  __syncthreads();
  if (tid < RR)
    scores[r0 + tid] = sred[0][tid] + sred[1][tid] + sred[2][tid] + sred[3][tid];
}

// -------- masked softmax over N per batch; alpha to d_out --------
__global__ __launch_bounds__(256)
void softmax_kernel(const float* __restrict__ scores, const int* __restrict__ mask,
                    float* __restrict__ alpha) {
  const int b = blockIdx.x, tid = threadIdx.x;
  const int base = b * NN;
  float vals[8];
  float mx = -3.4e38f;
  #pragma unroll
  for (int i = 0; i < 8; ++i) {
    int n = tid + 256 * i;
    float s = scores[base + n];
    if (mask[base + n] == 0) s = NEG_INF;
    vals[i] = s;
    mx = fmaxf(mx, s);
  }
  #pragma unroll
  for (int o = 32; o; o >>= 1) mx = fmaxf(mx, __shfl_xor(mx, o, 64));
  __shared__ float w4[4];
  if ((tid & 63) == 0) w4[tid >> 6] = mx;
  __syncthreads();
  mx = fmaxf(fmaxf(w4[0], w4[1]), fmaxf(w4[2], w4[3]));
  float sum = 0.f;
  #pragma unroll
  for (int i = 0; i < 8; ++i) { vals[i] = __expf(vals[i] - mx); sum += vals[i]; }
  #pragma unroll
  for (int o = 32; o; o >>= 1) sum += __shfl_xor(sum, o, 64);
  __shared__ float s4[4];
  if ((tid & 63) == 0) s4[tid >> 6] = sum;
  __syncthreads();
  sum = s4[0] + s4[1] + s4[2] + s4[3];
  float inv = 1.f / sum;
  #pragma unroll
  for (int i = 0; i < 8; ++i) alpha[base + tid + 256 * i] = vals[i] * inv;
}

// -------- context partials: 2048 blocks (64-row chunks), 2 accumulators --------
__global__ __launch_bounds__(128)
void context_part(const float* __restrict__ enc, const float* __restrict__ alpha,
                  float* __restrict__ cpart) {
  const int b  = blockIdx.x;
  const int nc = blockIdx.y;     // 32 chunks of 64 n
  const int t  = threadIdx.x;
  __shared__ float aL[64];
  if (t < 64) aL[t] = alpha[b * NN + nc * 64 + t];
  __syncthreads();
  const float* ep = enc + ((size_t)b * NN + nc * 64) * DD + t * 4;
  float4 a0 = {0.f, 0.f, 0.f, 0.f}, a1 = {0.f, 0.f, 0.f, 0.f};
  #pragma unroll 4
  for (int n = 0; n < 64; n += 2) {
    float4 e0 = *(const float4*)(ep + (size_t)n * DD);
    float4 e1 = *(const float4*)(ep + (size_t)(n + 1) * DD);
    float s0 = aL[n], s1 = aL[n + 1];
    a0.x += s0 * e0.x; a0.y += s0 * e0.y; a0.z += s0 * e0.z; a0.w += s0 * e0.w;
    a1.x += s1 * e1.x; a1.y += s1 * e1.y; a1.z += s1 * e1.z; a1.w += s1 * e1.w;
  }
  a0.x += a1.x; a0.y += a1.y; a0.z += a1.z; a0.w += a1.w;
  *(float4*)(cpart + ((size_t)(b * 32 + nc)) * DD + t * 4) = a0;
}

__global__ __launch_bounds__(256)
void context_reduce(const float* __restrict__ cpart, float* __restrict__ ctx) {
  const int i = blockIdx.x * 256 + threadIdx.x;   // 32768 = 64*512
  const int b = i >> 9, d = i & 511;
  float s = 0.f;
  #pragma unroll
  for (int nc = 0; nc < 32; ++nc) s += cpart[((size_t)(b * 32 + nc)) * DD + d];
  ctx[i] = s;
}

extern "C" void kernel_launch(void* const* d_in, const int* in_sizes, int n_in,
                              void* d_out, int out_size, void* d_ws, size_t ws_size,
                              hipStream_t stream) {
  const float* h    = (const float*)d_in[0];
  const float* enc  = (const float*)d_in[1];
  const int*   mask = (const int*)d_in[2];
  const float* Wh   = (const float*)d_in[3];
  const float* We   = (const float*)d_in[4];
  const float* v    = (const float*)d_in[5];

  float* out   = (float*)d_out;
  float* ctx   = out;                 // (B, D)
  float* alpha = out + BB * DD;       // (B, N)

  char* w = (char*)d_ws;
  unsigned short* web = (unsigned short*)w;                 // 512 KB
  float* ph     = (float*)(w + (size_t)AA * DD * 2);        // 128 KB
  float* scores = ph + BB * AA;                             // 512 KB
  float* cpart  = scores + BB * NN;                         // 4 MB

  we_cast_kernel<<<(AA * DD / 8 + 255) / 256, 256, 0, stream>>>(We, web);
  proj_h_kernel<<<dim3(BB, 2), 256, 0, stream>>>(h, Wh, ph);
  scores_fullk<<<(BB * NN) / 128, 512, 0, stream>>>(enc, web, ph, v, scores);
  softmax_kernel<<<BB, 256, 0, stream>>>(scores, mask, alpha);
  context_part<<<dim3(BB, 32), 128, 0, stream>>>(enc, alpha, cpart);
  context_reduce<<<(BB * DD) / 256, 256, 0, stream>>>(cpart, ctx);
  (void)in_sizes; (void)n_in; (void)out_size; (void)ws_size;
}